// Round 17
// baseline (967.376 us; speedup 1.0000x reference)
//
#include <hip/hip_runtime.h>
#include <hip/hip_bf16.h>

constexpr int B = 4, T = 8, N = 4096, C0 = 64, C1 = 128;
constexpr int M = 1024, KNN = 32;

typedef __attribute__((ext_vector_type(8))) short short8;
typedef __attribute__((ext_vector_type(4))) float f32x4;
typedef __attribute__((ext_vector_type(2))) float f32x2;

__device__ __forceinline__ unsigned short f2bf(float x) {
  unsigned u = __float_as_uint(x);
  u = u + 0x7FFFu + ((u >> 16) & 1u);
  return (unsigned short)(u >> 16);
}
__device__ __forceinline__ float bf2f(unsigned short h) {
  return __uint_as_float((unsigned)h << 16);
}
__device__ __forceinline__ short f2bf_rn(float x) {
  union { __hip_bfloat16 b; unsigned short u; } v;
  v.b = __float2bfloat16(x);
  return (short)v.u;
}

template <int CTRL>
__device__ __forceinline__ float dppf(float x) {
  return __int_as_float(__builtin_amdgcn_update_dpp(0, __float_as_int(x), CTRL, 0xF, 0xF, true));
}
template <int CTRL>
__device__ __forceinline__ int dppi(int x) {
  return __builtin_amdgcn_update_dpp(0, x, CTRL, 0xF, 0xF, true);
}
template <int CTRL>
__device__ __forceinline__ unsigned long long dppu64(unsigned long long x) {
  unsigned lo = (unsigned)dppi<CTRL>((int)(unsigned)x);
  unsigned hi = (unsigned)dppi<CTRL>((int)(unsigned)(x >> 32));
  return ((unsigned long long)hi << 32) | lo;
}
__device__ __forceinline__ void kmerge(unsigned long long& a, unsigned long long b) {
  if (b > a) a = b;
}
__device__ __forceinline__ unsigned long long kmax(unsigned long long a, unsigned long long b) {
  return b > a ? b : a;
}

// ---------------- prep: WfT[c][o] = Wf[o][c] --------------------------------
__global__ __launch_bounds__(256) void prep_wft(const float* __restrict__ Wf,
                                                float* __restrict__ WfT) {
  int t = blockIdx.x * 256 + threadIdx.x;
  if (t < 64 * 64) WfT[t] = Wf[(t & 63) * 64 + (t >> 6)];
}

// ---------------- prep: W1 -> MFMA A-fragment-ordered bf16 hi/lo ------------
__global__ __launch_bounds__(256) void prep_w1frag(const float* __restrict__ W1,
                                                   unsigned short* __restrict__ w1hi,
                                                   unsigned short* __restrict__ w1lo) {
  int t = blockIdx.x * 256 + threadIdx.x;
  if (t >= 8192) return;
  int j = t & 7, lane = (t >> 3) & 63, mt = (t >> 9) & 7, kt = t >> 12;
  int row = mt * 16 + (lane & 15);
  int k = kt * 32 + (lane >> 4) * 8 + j;
  float v = W1[row * 64 + k];
  unsigned short hi = f2bf(v);
  w1hi[t] = hi;
  w1lo[t] = f2bf(v - bf2f(hi));
}

// ---------------- fps v6: 8 waves (512 thr), 8 pts/lane, u64 keys -----------
__device__ void fps_body(char* smem, const float* __restrict__ xyz,
                         float* __restrict__ out_xyz, int bt) {
#pragma clang fp contract(off)
  float* xs = (float*)smem;  // 16 KB
  float* ys = xs + N;        // 16 KB
  float* zs = ys + N;        // 16 KB
  unsigned long long* wslot = (unsigned long long*)(smem + 49152);  // 2 bufs x 8
  const float* p = xyz + (size_t)bt * N * 3;
  int tid = threadIdx.x;
  int lane = tid & 63, w = tid >> 6;  // w in 0..7
  for (int i = tid; i < N; i += 512) {
    xs[i] = p[i * 3 + 0];
    ys[i] = p[i * 3 + 1];
    zs[i] = p[i * 3 + 2];
  }
  __syncthreads();
  f32x2 X2[4], Y2[4], Z2[4], D2[4];
  unsigned inv[8];
#pragma unroll
  for (int j = 0; j < 4; ++j) {
    int i0 = (2 * j) * 512 + tid, i1 = (2 * j + 1) * 512 + tid;
    X2[j] = (f32x2){xs[i0], xs[i1]};
    Y2[j] = (f32x2){ys[i0], ys[i1]};
    Z2[j] = (f32x2){zs[i0], zs[i1]};
    D2[j] = (f32x2){1e10f, 1e10f};
    inv[2 * j] = ~(unsigned)i0;
    inv[2 * j + 1] = ~(unsigned)i1;
  }
  if (tid == 0) {
    float* a0 = out_xyz + (size_t)bt * M * 3;
    a0[0] = xs[0]; a0[1] = ys[0]; a0[2] = zs[0];
  }
  int lidx = 0;
  for (int s = 1; s < M; ++s) {
    float lx = xs[lidx], ly = ys[lidx], lz = zs[lidx];
    if (tid == 0 && s > 1) {  // stream pick s-1 (coords = lp); store is async
      float* ap = out_xyz + ((size_t)(bt * M + s - 1)) * 3;
      ap[0] = lx; ap[1] = ly; ap[2] = lz;
    }
    f32x2 l2x = (f32x2){lx, lx}, l2y = (f32x2){ly, ly}, l2z = (f32x2){lz, lz};
    unsigned long long k[8];
#pragma unroll
    for (int j = 0; j < 4; ++j) {
      f32x2 dx = X2[j] - l2x;
      f32x2 dy = Y2[j] - l2y;
      f32x2 dz = Z2[j] - l2z;
      f32x2 d = dx * dx + dy * dy + dz * dz;  // contract(off): exact mul+add
      f32x2 nd = __builtin_elementwise_min(D2[j], d);
      D2[j] = nd;
      k[2 * j] = ((unsigned long long)__float_as_uint(nd.x) << 32) | inv[2 * j];
      k[2 * j + 1] = ((unsigned long long)__float_as_uint(nd.y) << 32) | inv[2 * j + 1];
    }
#pragma unroll
    for (int st = 4; st >= 1; st >>= 1)
#pragma unroll
      for (int j = 0; j < st; ++j) kmerge(k[j], k[j + st]);
    unsigned long long best = k[0];
    kmerge(best, dppu64<0xB1>(best));
    kmerge(best, dppu64<0x4E>(best));
    kmerge(best, dppu64<0x141>(best));
    kmerge(best, dppu64<0x140>(best));
    kmerge(best, dppu64<0x142>(best));  // row_bcast15
    kmerge(best, dppu64<0x143>(best));  // row_bcast31 -> lanes 48-63 = wave max
    int buf = s & 1;
    if (lane == 63) wslot[buf * 8 + w] = best;
    asm volatile("s_waitcnt lgkmcnt(0)" ::: "memory");
    __builtin_amdgcn_s_barrier();
    __builtin_amdgcn_sched_barrier(0);
    const ulonglong2* ws2 = (const ulonglong2*)&wslot[buf * 8];
    ulonglong2 a0 = ws2[0], a1 = ws2[1], a2 = ws2[2], a3 = ws2[3];
    unsigned long long g = kmax(kmax(kmax(a0.x, a0.y), kmax(a1.x, a1.y)),
                                kmax(kmax(a2.x, a2.y), kmax(a3.x, a3.y)));
    lidx = (int)(~(unsigned)g);
  }
  if (tid == 0) {
    float* ap = out_xyz + ((size_t)(bt * M + M - 1)) * 3;
    ap[0] = xs[lidx]; ap[1] = ys[lidx]; ap[2] = zs[lidx];
  }
}

// ---------------- rff tile (512 threads): RFFh[n] = bf16(relu(Wf @ f_n)) ----
__device__ void rff_body(char* smem, const float* __restrict__ f,
                         const float* __restrict__ WfT, unsigned short* __restrict__ RFFh,
                         int rid) {
  float (*tile)[65] = (float (*)[65])smem;  // 16.6 KB
  int bt = rid >> 6;
  int n0 = (rid & 63) * 64;
  const float* src = f + (size_t)bt * C0 * N;
  int tx = threadIdx.x & 63, ty = threadIdx.x >> 6;  // ty 0..7
  for (int r = ty; r < 64; r += 8)
    tile[r][tx] = src[(size_t)r * N + n0 + tx];
  __syncthreads();
  float acc[8];
#pragma unroll
  for (int oo = 0; oo < 8; ++oo) acc[oo] = 0.f;
  int obase = ty * 8;  // wave-uniform
#pragma unroll 4
  for (int c = 0; c < 64; ++c) {
    float fv = tile[c][tx];
    const float* wr = WfT + c * 64 + obase;
#pragma unroll
    for (int oo = 0; oo < 8; ++oo) acc[oo] = fmaf(fv, wr[oo], acc[oo]);
  }
  __syncthreads();
#pragma unroll
  for (int oo = 0; oo < 8; ++oo) tile[obase + oo][tx] = fmaxf(acc[oo], 0.f);
  __syncthreads();
  unsigned short* dst = RFFh + ((size_t)bt * N + n0) * 64;
  for (int r = ty; r < 64; r += 8)
    dst[(size_t)r * 64 + tx] = f2bf(tile[tx][r]);
}

__global__ __launch_bounds__(512) void fps_rff_kernel(const float* __restrict__ xyz,
                                                      float* __restrict__ out_xyz,
                                                      const float* __restrict__ feats,
                                                      const float* __restrict__ WfT,
                                                      unsigned short* __restrict__ RFFh) {
  __shared__ __align__(16) char smem[49152 + 256];
  if (blockIdx.x < 32)
    fps_body(smem, xyz, out_xyz, blockIdx.x);
  else
    rff_body(smem, feats, WfT, RFFh, blockIdx.x - 32);
}

// ---------------- ball query: one wave per (b,t,di,m), zero LDS -------------
__global__ __launch_bounds__(256) void ballq_kernel(const float* __restrict__ xyz,
                                                    const float* __restrict__ anchors,
                                                    int* __restrict__ idxbuf) {
  const float R2 = 0.04f;
  int w = threadIdx.x >> 6, lane = threadIdx.x & 63;
  int q = blockIdx.x * 4 + w;
  int m = q & (M - 1);
  int di = (q >> 10) % 3;
  int bt = q / (M * 3);
  int b = bt >> 3, t = bt & 7;
  int srct = t + di - 1;
  srct = srct < 0 ? 0 : (srct > 7 ? 7 : srct);
  const float* anc = anchors + ((size_t)(bt * M + m)) * 3;
  float ax = anc[0], ay = anc[1], az = anc[2];
  const float* pts = xyz + ((size_t)(b * T + srct)) * N * 3;
  int* outp = idxbuf + (size_t)q * KNN;
  int cnt = 0, first = 0;
  for (int c = 0; c < N / 64 && cnt < KNN; ++c) {
    int pi = c * 64 + lane;
    const float* pp = pts + (size_t)pi * 3;
    float dx = __fsub_rn(ax, pp[0]);
    float dy = __fsub_rn(ay, pp[1]);
    float dz = __fsub_rn(az, pp[2]);
    float d2 = __fadd_rn(__fadd_rn(__fmul_rn(dx, dx), __fmul_rn(dy, dy)), __fmul_rn(dz, dz));
    bool hit = d2 < R2;
    unsigned long long mask = __ballot(hit);
    if (cnt == 0 && mask) first = c * 64 + (int)__builtin_ctzll(mask);
    int prefix = (int)__popcll(mask & ((1ull << lane) - 1ull));
    int slot = cnt + prefix;
    if (hit && slot < KNN) outp[slot] = pi;
    cnt += (int)__popcll(mask);
  }
  int cntK = cnt < KNN ? cnt : KNN;
  int fill = (cnt == 0) ? 0 : first;
  if (lane < KNN && lane >= cntK) outp[lane] = fill;
}

// ---------------- fused gather(bf16) + dfeat + MFMA layer2 (R10-proven) -----
__global__ __launch_bounds__(256) void mlp_kernel(const float* __restrict__ xyz,
                                                  const unsigned short* __restrict__ RFFh,
                                                  const unsigned short* __restrict__ w1hi,
                                                  const unsigned short* __restrict__ w1lo,
                                                  const float* __restrict__ Wd,
                                                  const float* __restrict__ anchors,
                                                  const int* __restrict__ idxbuf,
                                                  float* __restrict__ out_feats) {
  __shared__ unsigned short Ah[8192];
  __shared__ unsigned short Al[8192];
  __shared__ float wd_l[256];
  __shared__ float fstage[4][128];
  int tid = threadIdx.x;
  {
    uint4* dh = (uint4*)Ah;
    const uint4* sh = (const uint4*)w1hi;
    uint4* dl = (uint4*)Al;
    const uint4* sl = (const uint4*)w1lo;
    for (int i = tid; i < 1024; i += 256) { dh[i] = sh[i]; dl[i] = sl[i]; }
    wd_l[tid] = Wd[tid];
  }
  __syncthreads();
  int w = tid >> 6, lane = tid & 63;
  int nloc = lane & 15, grp = lane >> 4;
  // XCD-aware swizzle: 8192 blocks, 8 XCDs -> each XCD gets 1024 contiguous
  int bid = blockIdx.x;
  int swz = ((bid & 7) << 10) | (bid >> 3);
  int bt = swz >> 8;
  int m0 = (swz & 255) * 4;
  int m = m0 + w;
  int b = bt >> 3, t = bt & 7;
  int aoff = __builtin_amdgcn_readfirstlane(bt * M + m);
  float ax = anchors[(size_t)aoff * 3 + 0];
  float ay = anchors[(size_t)aoff * 3 + 1];
  float az = anchors[(size_t)aoff * 3 + 2];
  f32x4 acc[8];
#pragma unroll
  for (int mt = 0; mt < 8; ++mt) acc[mt] = (f32x4){0.f, 0.f, 0.f, 0.f};

  short8 pg0[2][2], pg1[2][2];  // [buf][kt] bf16 rff fragments
  float ppx[2][2], ppy[2][2], ppz[2][2];

#define MLOADP(BUF, DI)                                                        \
  {                                                                            \
    int srct = t + (DI)-1;                                                     \
    srct = srct < 0 ? 0 : (srct > 7 ? 7 : srct);                               \
    const unsigned short* rf = RFFh + ((size_t)(b * T + srct)) * N * 64;       \
    const float* pts = xyz + ((size_t)(b * T + srct)) * N * 3;                 \
    const int* ip = idxbuf + ((size_t)((bt * 3 + (DI)) * M + m)) * KNN;        \
    int n0 = ip[nloc], n1 = ip[16 + nloc];                                     \
    _Pragma("unroll") for (int kt = 0; kt < 2; ++kt) {                         \
      pg0[BUF][kt] = *(const short8*)(rf + (size_t)n0 * 64 + kt * 32 + grp * 8); \
      pg1[BUF][kt] = *(const short8*)(rf + (size_t)n1 * 64 + kt * 32 + grp * 8); \
    }                                                                          \
    ppx[BUF][0] = pts[n0 * 3 + 0];                                             \
    ppy[BUF][0] = pts[n0 * 3 + 1];                                             \
    ppz[BUF][0] = pts[n0 * 3 + 2];                                             \
    ppx[BUF][1] = pts[n1 * 3 + 0];                                             \
    ppy[BUF][1] = pts[n1 * 3 + 1];                                             \
    ppz[BUF][1] = pts[n1 * 3 + 2];                                             \
  }

#define MCOMPUTE(BUF, DI)                                                      \
  {                                                                            \
    int zro = 0;                                                               \
    asm volatile("" : "+v"(zro));                                              \
    const unsigned short* AhO = Ah + zro;                                      \
    const unsigned short* AlO = Al + zro;                                      \
    const float* wdO = (const float*)wd_l + zro;                               \
    float tvv = (float)((DI)-1);                                               \
    float dx0 = ppx[BUF][0] - ax, dy0 = ppy[BUF][0] - ay, dz0 = ppz[BUF][0] - az; \
    float dx1 = ppx[BUF][1] - ax, dy1 = ppy[BUF][1] - ay, dz1 = ppz[BUF][1] - az; \
    short8 Bh[2][2]; /* [kt][nt] */                                            \
    _Pragma("unroll") for (int kt = 0; kt < 2; ++kt) {                         \
      short8 bh0, bh1;                                                         \
      _Pragma("unroll") for (int j = 0; j < 8; ++j) {                          \
        int ch = kt * 32 + grp * 8 + j;                                        \
        float4 wr = *(const float4*)&wdO[ch * 4];                              \
        float dd0 = fmaf(dx0, wr.x, fmaf(dy0, wr.y, fmaf(dz0, wr.z, tvv * wr.w))); \
        float dd1 = fmaf(dx1, wr.x, fmaf(dy1, wr.y, fmaf(dz1, wr.z, tvv * wr.w))); \
        float h0 = bf2f((unsigned short)pg0[BUF][kt][j]) + fmaxf(dd0, 0.f);    \
        float h1 = bf2f((unsigned short)pg1[BUF][kt][j]) + fmaxf(dd1, 0.f);    \
        bh0[j] = f2bf_rn(h0);                                                  \
        bh1[j] = f2bf_rn(h1);                                                  \
      }                                                                        \
      Bh[kt][0] = bh0;                                                         \
      Bh[kt][1] = bh1;                                                         \
    }                                                                          \
    _Pragma("unroll") for (int hf = 0; hf < 2; ++hf) {                         \
      f32x4 c[4][2];                                                           \
      _Pragma("unroll") for (int mq = 0; mq < 4; ++mq) {                       \
        c[mq][0] = (f32x4){0.f, 0.f, 0.f, 0.f};                                \
        c[mq][1] = (f32x4){0.f, 0.f, 0.f, 0.f};                                \
      }                                                                        \
      _Pragma("unroll") for (int kt = 0; kt < 2; ++kt) {                       \
        _Pragma("unroll") for (int mq = 0; mq < 4; ++mq) {                     \
          int fo = ((kt * 8 + hf * 4 + mq) * 64 + lane) * 8;                   \
          short8 ahf = *(const short8*)&AhO[fo];                               \
          short8 alf = *(const short8*)&AlO[fo];                               \
          c[mq][0] =                                                           \
              __builtin_amdgcn_mfma_f32_16x16x32_bf16(ahf, Bh[kt][0], c[mq][0], 0, 0, 0); \
          c[mq][0] =                                                           \
              __builtin_amdgcn_mfma_f32_16x16x32_bf16(alf, Bh[kt][0], c[mq][0], 0, 0, 0); \
          c[mq][1] =                                                           \
              __builtin_amdgcn_mfma_f32_16x16x32_bf16(ahf, Bh[kt][1], c[mq][1], 0, 0, 0); \
          c[mq][1] =                                                           \
              __builtin_amdgcn_mfma_f32_16x16x32_bf16(alf, Bh[kt][1], c[mq][1], 0, 0, 0); \
        }                                                                      \
      }                                                                        \
      _Pragma("unroll") for (int mq = 0; mq < 4; ++mq)                         \
          _Pragma("unroll") for (int r = 0; r < 4; ++r) {                      \
        float o = fmaxf(c[mq][0][r], c[mq][1][r]);                             \
        o = fmaxf(o, dppf<0xB1>(o));                                           \
        o = fmaxf(o, dppf<0x4E>(o));                                           \
        o = fmaxf(o, dppf<0x141>(o));                                          \
        o = fmaxf(o, dppf<0x140>(o));                                          \
        acc[hf * 4 + mq][r] += fmaxf(o, 0.f);                                  \
      }                                                                        \
    }                                                                          \
  }

  MLOADP(0, 0)
  MLOADP(1, 1)
  MCOMPUTE(0, 0)
  MLOADP(0, 2)
  MCOMPUTE(1, 1)
  MCOMPUTE(0, 2)
#undef MLOADP
#undef MCOMPUTE

  if (nloc == 0) {
#pragma unroll
    for (int mt = 0; mt < 8; ++mt)
#pragma unroll
      for (int r = 0; r < 4; ++r)
        fstage[w][mt * 16 + grp * 4 + r] = acc[mt][r];
  }
  __syncthreads();
  if (tid < 128) {
    float4 v = make_float4(fstage[0][tid], fstage[1][tid], fstage[2][tid], fstage[3][tid]);
    *(float4*)&out_feats[((size_t)(bt * C1 + tid)) * M + m0] = v;
  }
}

extern "C" void kernel_launch(void* const* d_in, const int* in_sizes, int n_in,
                              void* d_out, int out_size, void* d_ws, size_t ws_size,
                              hipStream_t stream) {
  const float* xyzs = (const float*)d_in[0];
  const float* feats = (const float*)d_in[1];
  const float* Wd = (const float*)d_in[2];
  const float* Wf = (const float*)d_in[3];
  const float* W1 = (const float*)d_in[4];
  float* out_xyz = (float*)d_out;                            // (B,8,M,3)
  float* out_feats = (float*)d_out + (size_t)B * T * M * 3;  // (B,8,C1,M)
  char* ws = (char*)d_ws;
  unsigned short* RFFh = (unsigned short*)ws;                       // 16.78 MB
  int* idxbuf = (int*)(ws + (size_t)B * T * N * 64 * 2);            // 12.58 MB
  char* tail = ws + (size_t)B * T * N * 64 * 2 + (size_t)B * T * 3 * M * KNN * 4;
  float* WfT = (float*)tail;                                        // 16 KB
  unsigned short* w1hi = (unsigned short*)(tail + 16384);           // 16 KB
  unsigned short* w1lo = (unsigned short*)(tail + 32768);           // 16 KB
  prep_wft<<<16, 256, 0, stream>>>(Wf, WfT);
  prep_w1frag<<<32, 256, 0, stream>>>(W1, w1hi, w1lo);
  fps_rff_kernel<<<32 + 2048, 512, 0, stream>>>(xyzs, out_xyz, feats, WfT, RFFh);
  ballq_kernel<<<(B * T * 3 * M) / 4, 256, 0, stream>>>(xyzs, out_xyz, idxbuf);
  mlp_kernel<<<(B * T * M) / 4, 256, 0, stream>>>(xyzs, RFFh, w1hi, w1lo, Wd, out_xyz,
                                                  idxbuf, out_feats);
}

// Round 18
// 917.589 us; speedup vs baseline: 1.0543x; 1.0543x over previous
//
#include <hip/hip_runtime.h>
#include <hip/hip_bf16.h>

constexpr int B = 4, T = 8, N = 4096, C0 = 64, C1 = 128;
constexpr int M = 1024, KNN = 32;

typedef __attribute__((ext_vector_type(8))) short short8;
typedef __attribute__((ext_vector_type(4))) float f32x4;
typedef __attribute__((ext_vector_type(2))) float f32x2;

__device__ __forceinline__ unsigned short f2bf(float x) {
  unsigned u = __float_as_uint(x);
  u = u + 0x7FFFu + ((u >> 16) & 1u);
  return (unsigned short)(u >> 16);
}
__device__ __forceinline__ float bf2f(unsigned short h) {
  return __uint_as_float((unsigned)h << 16);
}
__device__ __forceinline__ short f2bf_rn(float x) {
  union { __hip_bfloat16 b; unsigned short u; } v;
  v.b = __float2bfloat16(x);
  return (short)v.u;
}

template <int CTRL>
__device__ __forceinline__ float dppf(float x) {
  return __int_as_float(__builtin_amdgcn_update_dpp(0, __float_as_int(x), CTRL, 0xF, 0xF, true));
}
template <int CTRL>
__device__ __forceinline__ int dppi(int x) {
  return __builtin_amdgcn_update_dpp(0, x, CTRL, 0xF, 0xF, true);
}
template <int CTRL>
__device__ __forceinline__ unsigned long long dppu64(unsigned long long x) {
  unsigned lo = (unsigned)dppi<CTRL>((int)(unsigned)x);
  unsigned hi = (unsigned)dppi<CTRL>((int)(unsigned)(x >> 32));
  return ((unsigned long long)hi << 32) | lo;
}
__device__ __forceinline__ void kmerge(unsigned long long& a, unsigned long long b) {
  if (b > a) a = b;
}
__device__ __forceinline__ unsigned long long kmax(unsigned long long a, unsigned long long b) {
  return b > a ? b : a;
}

// ---------------- prep: WfT[c][o] = Wf[o][c] --------------------------------
__global__ __launch_bounds__(256) void prep_wft(const float* __restrict__ Wf,
                                                float* __restrict__ WfT) {
  int t = blockIdx.x * 256 + threadIdx.x;
  if (t < 64 * 64) WfT[t] = Wf[(t & 63) * 64 + (t >> 6)];
}

// ---------------- prep: W1 -> MFMA A-fragment-ordered bf16 (hi only) --------
__global__ __launch_bounds__(256) void prep_w1frag(const float* __restrict__ W1,
                                                   unsigned short* __restrict__ w1hi) {
  int t = blockIdx.x * 256 + threadIdx.x;
  if (t >= 8192) return;
  int j = t & 7, lane = (t >> 3) & 63, mt = (t >> 9) & 7, kt = t >> 12;
  int row = mt * 16 + (lane & 15);
  int k = kt * 32 + (lane >> 4) * 8 + j;
  w1hi[t] = f2bf(W1[row * 64 + k]);
}

// ---------------- fps v5: 4 waves, f32x2-packed update, 6-hop DPP, 4 slots --
__device__ void fps_body(char* smem, const float* __restrict__ xyz,
                         float* __restrict__ out_xyz, int bt) {
#pragma clang fp contract(off)
  float* xs = (float*)smem;  // 16 KB
  float* ys = xs + N;        // 16 KB
  float* zs = ys + N;        // 16 KB
  unsigned long long* wslot = (unsigned long long*)(smem + 49152);  // 2 bufs x 4
  const float* p = xyz + (size_t)bt * N * 3;
  int tid = threadIdx.x;
  int lane = tid & 63, w = tid >> 6;
  for (int i = tid; i < N; i += 256) {
    xs[i] = p[i * 3 + 0];
    ys[i] = p[i * 3 + 1];
    zs[i] = p[i * 3 + 2];
  }
  __syncthreads();
  f32x2 X2[8], Y2[8], Z2[8], D2[8];
  unsigned inv[16];
#pragma unroll
  for (int j = 0; j < 8; ++j) {
    int i0 = (2 * j) * 256 + tid, i1 = (2 * j + 1) * 256 + tid;
    X2[j] = (f32x2){xs[i0], xs[i1]};
    Y2[j] = (f32x2){ys[i0], ys[i1]};
    Z2[j] = (f32x2){zs[i0], zs[i1]};
    D2[j] = (f32x2){1e10f, 1e10f};
    inv[2 * j] = ~(unsigned)i0;
    inv[2 * j + 1] = ~(unsigned)i1;
  }
  if (tid == 0) {
    float* a0 = out_xyz + (size_t)bt * M * 3;
    a0[0] = xs[0]; a0[1] = ys[0]; a0[2] = zs[0];
  }
  int lidx = 0;
  for (int s = 1; s < M; ++s) {
    float lx = xs[lidx], ly = ys[lidx], lz = zs[lidx];
    if (tid == 0 && s > 1) {  // stream pick s-1 (coords = lp); store is async
      float* ap = out_xyz + ((size_t)(bt * M + s - 1)) * 3;
      ap[0] = lx; ap[1] = ly; ap[2] = lz;
    }
    f32x2 l2x = (f32x2){lx, lx}, l2y = (f32x2){ly, ly}, l2z = (f32x2){lz, lz};
    unsigned long long k[16];
#pragma unroll
    for (int j = 0; j < 8; ++j) {
      f32x2 dx = X2[j] - l2x;
      f32x2 dy = Y2[j] - l2y;
      f32x2 dz = Z2[j] - l2z;
      f32x2 d = dx * dx + dy * dy + dz * dz;  // contract(off): exact mul+add
      f32x2 nd = __builtin_elementwise_min(D2[j], d);
      D2[j] = nd;
      k[2 * j] = ((unsigned long long)__float_as_uint(nd.x) << 32) | inv[2 * j];
      k[2 * j + 1] = ((unsigned long long)__float_as_uint(nd.y) << 32) | inv[2 * j + 1];
    }
#pragma unroll
    for (int st = 8; st >= 1; st >>= 1)
#pragma unroll
      for (int j = 0; j < st; ++j) kmerge(k[j], k[j + st]);
    unsigned long long best = k[0];
    kmerge(best, dppu64<0xB1>(best));
    kmerge(best, dppu64<0x4E>(best));
    kmerge(best, dppu64<0x141>(best));
    kmerge(best, dppu64<0x140>(best));
    kmerge(best, dppu64<0x142>(best));  // row_bcast15
    kmerge(best, dppu64<0x143>(best));  // row_bcast31 -> lanes 48-63 = wave max
    int buf = s & 1;
    if (lane == 63) wslot[buf * 4 + w] = best;
    asm volatile("s_waitcnt lgkmcnt(0)" ::: "memory");
    __builtin_amdgcn_s_barrier();
    __builtin_amdgcn_sched_barrier(0);
    const ulonglong2* ws2 = (const ulonglong2*)&wslot[buf * 4];
    ulonglong2 a0 = ws2[0], a1 = ws2[1];
    unsigned long long g = kmax(kmax(a0.x, a0.y), kmax(a1.x, a1.y));
    lidx = (int)(~(unsigned)g);
  }
  if (tid == 0) {
    float* ap = out_xyz + ((size_t)(bt * M + M - 1)) * 3;
    ap[0] = xs[lidx]; ap[1] = ys[lidx]; ap[2] = zs[lidx];
  }
}

// ---------------- rff tile: RFFh[n] = bf16(relu(Wf @ f_n)) ------------------
__device__ void rff_body(char* smem, const float* __restrict__ f,
                         const float* __restrict__ WfT, unsigned short* __restrict__ RFFh,
                         int rid) {
  float (*tile)[65] = (float (*)[65])smem;  // 16.6 KB
  int bt = rid >> 6;
  int n0 = (rid & 63) * 64;
  const float* src = f + (size_t)bt * C0 * N;
  int tx = threadIdx.x & 63, ty = threadIdx.x >> 6;
  for (int r = ty; r < 64; r += 4)
    tile[r][tx] = src[(size_t)r * N + n0 + tx];
  __syncthreads();
  float acc[16];
#pragma unroll
  for (int oo = 0; oo < 16; ++oo) acc[oo] = 0.f;
  int obase = ty * 16;
#pragma unroll 4
  for (int c = 0; c < 64; ++c) {
    float fv = tile[c][tx];
    const float* wr = WfT + c * 64 + obase;
#pragma unroll
    for (int oo = 0; oo < 16; ++oo) acc[oo] = fmaf(fv, wr[oo], acc[oo]);
  }
  __syncthreads();
#pragma unroll
  for (int oo = 0; oo < 16; ++oo) tile[obase + oo][tx] = fmaxf(acc[oo], 0.f);
  __syncthreads();
  unsigned short* dst = RFFh + ((size_t)bt * N + n0) * 64;
  for (int r = ty; r < 64; r += 4)
    dst[(size_t)r * 64 + tx] = f2bf(tile[tx][r]);
}

__global__ __launch_bounds__(256) void fps_rff_kernel(const float* __restrict__ xyz,
                                                      float* __restrict__ out_xyz,
                                                      const float* __restrict__ feats,
                                                      const float* __restrict__ WfT,
                                                      unsigned short* __restrict__ RFFh) {
  __shared__ __align__(16) char smem[49152 + 256];
  if (blockIdx.x < 32)
    fps_body(smem, xyz, out_xyz, blockIdx.x);
  else
    rff_body(smem, feats, WfT, RFFh, blockIdx.x - 32);
}

// ---------------- ball query: one wave per (b,t,di,m), zero LDS -------------
__global__ __launch_bounds__(256) void ballq_kernel(const float* __restrict__ xyz,
                                                    const float* __restrict__ anchors,
                                                    int* __restrict__ idxbuf) {
  const float R2 = 0.04f;
  int w = threadIdx.x >> 6, lane = threadIdx.x & 63;
  int q = blockIdx.x * 4 + w;
  int m = q & (M - 1);
  int di = (q >> 10) % 3;
  int bt = q / (M * 3);
  int b = bt >> 3, t = bt & 7;
  int srct = t + di - 1;
  srct = srct < 0 ? 0 : (srct > 7 ? 7 : srct);
  const float* anc = anchors + ((size_t)(bt * M + m)) * 3;
  float ax = anc[0], ay = anc[1], az = anc[2];
  const float* pts = xyz + ((size_t)(b * T + srct)) * N * 3;
  int* outp = idxbuf + (size_t)q * KNN;
  int cnt = 0, first = 0;
  for (int c = 0; c < N / 64 && cnt < KNN; ++c) {
    int pi = c * 64 + lane;
    const float* pp = pts + (size_t)pi * 3;
    float dx = __fsub_rn(ax, pp[0]);
    float dy = __fsub_rn(ay, pp[1]);
    float dz = __fsub_rn(az, pp[2]);
    float d2 = __fadd_rn(__fadd_rn(__fmul_rn(dx, dx), __fmul_rn(dy, dy)), __fmul_rn(dz, dz));
    bool hit = d2 < R2;
    unsigned long long mask = __ballot(hit);
    if (cnt == 0 && mask) first = c * 64 + (int)__builtin_ctzll(mask);
    int prefix = (int)__popcll(mask & ((1ull << lane) - 1ull));
    int slot = cnt + prefix;
    if (hit && slot < KNN) outp[slot] = pi;
    cnt += (int)__popcll(mask);
  }
  int cntK = cnt < KNN ? cnt : KNN;
  int fill = (cnt == 0) ? 0 : first;
  if (lane < KNN && lane >= cntK) outp[lane] = fill;
}

// ---------------- fused gather(bf16) + dfeat + MFMA layer2 (hi-only W1) -----
__global__ __launch_bounds__(256) void mlp_kernel(const float* __restrict__ xyz,
                                                  const unsigned short* __restrict__ RFFh,
                                                  const unsigned short* __restrict__ w1hi,
                                                  const float* __restrict__ Wd,
                                                  const float* __restrict__ anchors,
                                                  const int* __restrict__ idxbuf,
                                                  float* __restrict__ out_feats) {
  __shared__ unsigned short Ah[8192];
  __shared__ float wd_l[256];
  __shared__ float fstage[4][128];
  int tid = threadIdx.x;
  {
    uint4* dh = (uint4*)Ah;
    const uint4* sh = (const uint4*)w1hi;
    for (int i = tid; i < 1024; i += 256) dh[i] = sh[i];
    wd_l[tid] = Wd[tid];
  }
  __syncthreads();
  int w = tid >> 6, lane = tid & 63;
  int nloc = lane & 15, grp = lane >> 4;
  // XCD-aware swizzle: 8192 blocks, 8 XCDs -> each XCD gets 1024 contiguous
  int bid = blockIdx.x;
  int swz = ((bid & 7) << 10) | (bid >> 3);
  int bt = swz >> 8;
  int m0 = (swz & 255) * 4;
  int m = m0 + w;
  int b = bt >> 3, t = bt & 7;
  int aoff = __builtin_amdgcn_readfirstlane(bt * M + m);
  float ax = anchors[(size_t)aoff * 3 + 0];
  float ay = anchors[(size_t)aoff * 3 + 1];
  float az = anchors[(size_t)aoff * 3 + 2];
  f32x4 acc[8];
#pragma unroll
  for (int mt = 0; mt < 8; ++mt) acc[mt] = (f32x4){0.f, 0.f, 0.f, 0.f};

  short8 pg0[2][2], pg1[2][2];  // [buf][kt] bf16 rff fragments
  float ppx[2][2], ppy[2][2], ppz[2][2];

#define MLOADP(BUF, DI)                                                        \
  {                                                                            \
    int srct = t + (DI)-1;                                                     \
    srct = srct < 0 ? 0 : (srct > 7 ? 7 : srct);                               \
    const unsigned short* rf = RFFh + ((size_t)(b * T + srct)) * N * 64;       \
    const float* pts = xyz + ((size_t)(b * T + srct)) * N * 3;                 \
    const int* ip = idxbuf + ((size_t)((bt * 3 + (DI)) * M + m)) * KNN;        \
    int n0 = ip[nloc], n1 = ip[16 + nloc];                                     \
    _Pragma("unroll") for (int kt = 0; kt < 2; ++kt) {                         \
      pg0[BUF][kt] = *(const short8*)(rf + (size_t)n0 * 64 + kt * 32 + grp * 8); \
      pg1[BUF][kt] = *(const short8*)(rf + (size_t)n1 * 64 + kt * 32 + grp * 8); \
    }                                                                          \
    ppx[BUF][0] = pts[n0 * 3 + 0];                                             \
    ppy[BUF][0] = pts[n0 * 3 + 1];                                             \
    ppz[BUF][0] = pts[n0 * 3 + 2];                                             \
    ppx[BUF][1] = pts[n1 * 3 + 0];                                             \
    ppy[BUF][1] = pts[n1 * 3 + 1];                                             \
    ppz[BUF][1] = pts[n1 * 3 + 2];                                             \
  }

#define MCOMPUTE(BUF, DI)                                                      \
  {                                                                            \
    int zro = 0;                                                               \
    asm volatile("" : "+v"(zro));                                              \
    const unsigned short* AhO = Ah + zro;                                      \
    const float* wdO = (const float*)wd_l + zro;                               \
    float tvv = (float)((DI)-1);                                               \
    float dx0 = ppx[BUF][0] - ax, dy0 = ppy[BUF][0] - ay, dz0 = ppz[BUF][0] - az; \
    float dx1 = ppx[BUF][1] - ax, dy1 = ppy[BUF][1] - ay, dz1 = ppz[BUF][1] - az; \
    short8 Bh[2][2]; /* [kt][nt] */                                            \
    _Pragma("unroll") for (int kt = 0; kt < 2; ++kt) {                         \
      short8 bh0, bh1;                                                         \
      _Pragma("unroll") for (int j = 0; j < 8; ++j) {                          \
        int ch = kt * 32 + grp * 8 + j;                                        \
        float4 wr = *(const float4*)&wdO[ch * 4];                              \
        float dd0 = fmaf(dx0, wr.x, fmaf(dy0, wr.y, fmaf(dz0, wr.z, tvv * wr.w))); \
        float dd1 = fmaf(dx1, wr.x, fmaf(dy1, wr.y, fmaf(dz1, wr.z, tvv * wr.w))); \
        float h0 = bf2f((unsigned short)pg0[BUF][kt][j]) + fmaxf(dd0, 0.f);    \
        float h1 = bf2f((unsigned short)pg1[BUF][kt][j]) + fmaxf(dd1, 0.f);    \
        bh0[j] = f2bf_rn(h0);                                                  \
        bh1[j] = f2bf_rn(h1);                                                  \
      }                                                                        \
      Bh[kt][0] = bh0;                                                         \
      Bh[kt][1] = bh1;                                                         \
    }                                                                          \
    _Pragma("unroll") for (int hf = 0; hf < 2; ++hf) {                         \
      f32x4 c[4][2];                                                           \
      _Pragma("unroll") for (int mq = 0; mq < 4; ++mq) {                       \
        c[mq][0] = (f32x4){0.f, 0.f, 0.f, 0.f};                                \
        c[mq][1] = (f32x4){0.f, 0.f, 0.f, 0.f};                                \
      }                                                                        \
      _Pragma("unroll") for (int kt = 0; kt < 2; ++kt) {                       \
        _Pragma("unroll") for (int mq = 0; mq < 4; ++mq) {                     \
          int fo = ((kt * 8 + hf * 4 + mq) * 64 + lane) * 8;                   \
          short8 ahf = *(const short8*)&AhO[fo];                               \
          c[mq][0] =                                                           \
              __builtin_amdgcn_mfma_f32_16x16x32_bf16(ahf, Bh[kt][0], c[mq][0], 0, 0, 0); \
          c[mq][1] =                                                           \
              __builtin_amdgcn_mfma_f32_16x16x32_bf16(ahf, Bh[kt][1], c[mq][1], 0, 0, 0); \
        }                                                                      \
      }                                                                        \
      _Pragma("unroll") for (int mq = 0; mq < 4; ++mq)                         \
          _Pragma("unroll") for (int r = 0; r < 4; ++r) {                      \
        float o = fmaxf(c[mq][0][r], c[mq][1][r]);                             \
        o = fmaxf(o, dppf<0xB1>(o));                                           \
        o = fmaxf(o, dppf<0x4E>(o));                                           \
        o = fmaxf(o, dppf<0x141>(o));                                          \
        o = fmaxf(o, dppf<0x140>(o));                                          \
        acc[hf * 4 + mq][r] += fmaxf(o, 0.f);                                  \
      }                                                                        \
    }                                                                          \
  }

  MLOADP(0, 0)
  MLOADP(1, 1)
  MCOMPUTE(0, 0)
  MLOADP(0, 2)
  MCOMPUTE(1, 1)
  MCOMPUTE(0, 2)
#undef MLOADP
#undef MCOMPUTE

  if (nloc == 0) {
#pragma unroll
    for (int mt = 0; mt < 8; ++mt)
#pragma unroll
      for (int r = 0; r < 4; ++r)
        fstage[w][mt * 16 + grp * 4 + r] = acc[mt][r];
  }
  __syncthreads();
  if (tid < 128) {
    float4 v = make_float4(fstage[0][tid], fstage[1][tid], fstage[2][tid], fstage[3][tid]);
    *(float4*)&out_feats[((size_t)(bt * C1 + tid)) * M + m0] = v;
  }
}

extern "C" void kernel_launch(void* const* d_in, const int* in_sizes, int n_in,
                              void* d_out, int out_size, void* d_ws, size_t ws_size,
                              hipStream_t stream) {
  const float* xyzs = (const float*)d_in[0];
  const float* feats = (const float*)d_in[1];
  const float* Wd = (const float*)d_in[2];
  const float* Wf = (const float*)d_in[3];
  const float* W1 = (const float*)d_in[4];
  float* out_xyz = (float*)d_out;                            // (B,8,M,3)
  float* out_feats = (float*)d_out + (size_t)B * T * M * 3;  // (B,8,C1,M)
  char* ws = (char*)d_ws;
  unsigned short* RFFh = (unsigned short*)ws;                       // 16.78 MB
  int* idxbuf = (int*)(ws + (size_t)B * T * N * 64 * 2);            // 12.58 MB
  char* tail = ws + (size_t)B * T * N * 64 * 2 + (size_t)B * T * 3 * M * KNN * 4;
  float* WfT = (float*)tail;                                        // 16 KB
  unsigned short* w1hi = (unsigned short*)(tail + 16384);           // 16 KB
  prep_wft<<<16, 256, 0, stream>>>(Wf, WfT);
  prep_w1frag<<<32, 256, 0, stream>>>(W1, w1hi);
  fps_rff_kernel<<<32 + 2048, 256, 0, stream>>>(xyzs, out_xyz, feats, WfT, RFFh);
  ballq_kernel<<<(B * T * 3 * M) / 4, 256, 0, stream>>>(xyzs, out_xyz, idxbuf);
  mlp_kernel<<<(B * T * M) / 4, 256, 0, stream>>>(xyzs, RFFh, w1hi, Wd, out_xyz,
                                                  idxbuf, out_feats);
}

// Round 19
// 913.324 us; speedup vs baseline: 1.0592x; 1.0047x over previous
//
#include <hip/hip_runtime.h>
#include <hip/hip_bf16.h>

constexpr int B = 4, T = 8, N = 4096, C0 = 64, C1 = 128;
constexpr int M = 1024, KNN = 32;

typedef __attribute__((ext_vector_type(8))) short short8;
typedef __attribute__((ext_vector_type(4))) float f32x4;
typedef __attribute__((ext_vector_type(2))) float f32x2;

__device__ __forceinline__ unsigned short f2bf(float x) {
  unsigned u = __float_as_uint(x);
  u = u + 0x7FFFu + ((u >> 16) & 1u);
  return (unsigned short)(u >> 16);
}
__device__ __forceinline__ float bf2f(unsigned short h) {
  return __uint_as_float((unsigned)h << 16);
}
__device__ __forceinline__ short f2bf_rn(float x) {
  union { __hip_bfloat16 b; unsigned short u; } v;
  v.b = __float2bfloat16(x);
  return (short)v.u;
}

template <int CTRL>
__device__ __forceinline__ float dppf(float x) {
  return __int_as_float(__builtin_amdgcn_update_dpp(0, __float_as_int(x), CTRL, 0xF, 0xF, true));
}
template <int CTRL>
__device__ __forceinline__ int dppi(int x) {
  return __builtin_amdgcn_update_dpp(0, x, CTRL, 0xF, 0xF, true);
}
template <int CTRL>
__device__ __forceinline__ unsigned long long dppu64(unsigned long long x) {
  unsigned lo = (unsigned)dppi<CTRL>((int)(unsigned)x);
  unsigned hi = (unsigned)dppi<CTRL>((int)(unsigned)(x >> 32));
  return ((unsigned long long)hi << 32) | lo;
}
__device__ __forceinline__ void kmerge(unsigned long long& a, unsigned long long b) {
  if (b > a) a = b;
}
__device__ __forceinline__ unsigned long long kmax(unsigned long long a, unsigned long long b) {
  return b > a ? b : a;
}

// ---------------- merged prep: WfT | w1hi frag | WdP pair-major -------------
// blocks 0-15: WfT[c][o]=Wf[o][c]; 16-47: w1hi frag; 48-51: WdP
__global__ __launch_bounds__(256) void prep_kernel(const float* __restrict__ Wf,
                                                   float* __restrict__ WfT,
                                                   const float* __restrict__ W1,
                                                   unsigned short* __restrict__ w1hi,
                                                   const float* __restrict__ Wd,
                                                   float* __restrict__ WdP) {
  int bid = blockIdx.x, tid = threadIdx.x;
  if (bid < 16) {
    int t = bid * 256 + tid;
    WfT[t] = Wf[(t & 63) * 64 + (t >> 6)];
  } else if (bid < 48) {
    int t = (bid - 16) * 256 + tid;
    int j = t & 7, lane = (t >> 3) & 63, mt = (t >> 9) & 7, kt = t >> 12;
    int row = mt * 16 + (lane & 15);
    int k = kt * 32 + (lane >> 4) * 8 + j;
    w1hi[t] = f2bf(W1[row * 64 + k]);
  } else {
    int t = (bid - 48) * 256 + tid;  // 0..1023
    int e = t & 1, c = (t >> 1) & 3, p = (t >> 3) & 3, grp = (t >> 5) & 7, kt = (t >> 8) & 1;
    int ch = kt * 32 + grp * 8 + 2 * p + e;
    WdP[t] = Wd[ch * 4 + c];
  }
}

// ---------------- fps v5: 4 waves, f32x2-packed update, 6-hop DPP, 4 slots --
__device__ void fps_body(char* smem, const float* __restrict__ xyz,
                         float* __restrict__ out_xyz, int bt) {
#pragma clang fp contract(off)
  float* xs = (float*)smem;  // 16 KB
  float* ys = xs + N;        // 16 KB
  float* zs = ys + N;        // 16 KB
  unsigned long long* wslot = (unsigned long long*)(smem + 49152);  // 2 bufs x 4
  const float* p = xyz + (size_t)bt * N * 3;
  int tid = threadIdx.x;
  int lane = tid & 63, w = tid >> 6;
  for (int i = tid; i < N; i += 256) {
    xs[i] = p[i * 3 + 0];
    ys[i] = p[i * 3 + 1];
    zs[i] = p[i * 3 + 2];
  }
  __syncthreads();
  f32x2 X2[8], Y2[8], Z2[8], D2[8];
  unsigned inv[16];
#pragma unroll
  for (int j = 0; j < 8; ++j) {
    int i0 = (2 * j) * 256 + tid, i1 = (2 * j + 1) * 256 + tid;
    X2[j] = (f32x2){xs[i0], xs[i1]};
    Y2[j] = (f32x2){ys[i0], ys[i1]};
    Z2[j] = (f32x2){zs[i0], zs[i1]};
    D2[j] = (f32x2){1e10f, 1e10f};
    inv[2 * j] = ~(unsigned)i0;
    inv[2 * j + 1] = ~(unsigned)i1;
  }
  if (tid == 0) {
    float* a0 = out_xyz + (size_t)bt * M * 3;
    a0[0] = xs[0]; a0[1] = ys[0]; a0[2] = zs[0];
  }
  int lidx = 0;
  for (int s = 1; s < M; ++s) {
    float lx = xs[lidx], ly = ys[lidx], lz = zs[lidx];
    if (tid == 0 && s > 1) {  // stream pick s-1 (coords = lp); store is async
      float* ap = out_xyz + ((size_t)(bt * M + s - 1)) * 3;
      ap[0] = lx; ap[1] = ly; ap[2] = lz;
    }
    f32x2 l2x = (f32x2){lx, lx}, l2y = (f32x2){ly, ly}, l2z = (f32x2){lz, lz};
    unsigned long long k[16];
#pragma unroll
    for (int j = 0; j < 8; ++j) {
      f32x2 dx = X2[j] - l2x;
      f32x2 dy = Y2[j] - l2y;
      f32x2 dz = Z2[j] - l2z;
      f32x2 d = dx * dx + dy * dy + dz * dz;  // contract(off): exact mul+add
      f32x2 nd = __builtin_elementwise_min(D2[j], d);
      D2[j] = nd;
      k[2 * j] = ((unsigned long long)__float_as_uint(nd.x) << 32) | inv[2 * j];
      k[2 * j + 1] = ((unsigned long long)__float_as_uint(nd.y) << 32) | inv[2 * j + 1];
    }
#pragma unroll
    for (int st = 8; st >= 1; st >>= 1)
#pragma unroll
      for (int j = 0; j < st; ++j) kmerge(k[j], k[j + st]);
    unsigned long long best = k[0];
    kmerge(best, dppu64<0xB1>(best));
    kmerge(best, dppu64<0x4E>(best));
    kmerge(best, dppu64<0x141>(best));
    kmerge(best, dppu64<0x140>(best));
    kmerge(best, dppu64<0x142>(best));  // row_bcast15
    kmerge(best, dppu64<0x143>(best));  // row_bcast31 -> lanes 48-63 = wave max
    int buf = s & 1;
    if (lane == 63) wslot[buf * 4 + w] = best;
    asm volatile("s_waitcnt lgkmcnt(0)" ::: "memory");
    __builtin_amdgcn_s_barrier();
    __builtin_amdgcn_sched_barrier(0);
    const ulonglong2* ws2 = (const ulonglong2*)&wslot[buf * 4];
    ulonglong2 a0 = ws2[0], a1 = ws2[1];
    unsigned long long g = kmax(kmax(a0.x, a0.y), kmax(a1.x, a1.y));
    lidx = (int)(~(unsigned)g);
  }
  if (tid == 0) {
    float* ap = out_xyz + ((size_t)(bt * M + M - 1)) * 3;
    ap[0] = xs[lidx]; ap[1] = ys[lidx]; ap[2] = zs[lidx];
  }
}

// ---------------- rff tile: RFFh[n] = bf16(relu(Wf @ f_n)) ------------------
__device__ void rff_body(char* smem, const float* __restrict__ f,
                         const float* __restrict__ WfT, unsigned short* __restrict__ RFFh,
                         int rid) {
  float (*tile)[65] = (float (*)[65])smem;  // 16.6 KB
  int bt = rid >> 6;
  int n0 = (rid & 63) * 64;
  const float* src = f + (size_t)bt * C0 * N;
  int tx = threadIdx.x & 63, ty = threadIdx.x >> 6;
  for (int r = ty; r < 64; r += 4)
    tile[r][tx] = src[(size_t)r * N + n0 + tx];
  __syncthreads();
  float acc[16];
#pragma unroll
  for (int oo = 0; oo < 16; ++oo) acc[oo] = 0.f;
  int obase = ty * 16;
#pragma unroll 4
  for (int c = 0; c < 64; ++c) {
    float fv = tile[c][tx];
    const float* wr = WfT + c * 64 + obase;
#pragma unroll
    for (int oo = 0; oo < 16; ++oo) acc[oo] = fmaf(fv, wr[oo], acc[oo]);
  }
  __syncthreads();
#pragma unroll
  for (int oo = 0; oo < 16; ++oo) tile[obase + oo][tx] = fmaxf(acc[oo], 0.f);
  __syncthreads();
  unsigned short* dst = RFFh + ((size_t)bt * N + n0) * 64;
  for (int r = ty; r < 64; r += 4)
    dst[(size_t)r * 64 + tx] = f2bf(tile[tx][r]);
}

__global__ __launch_bounds__(256) void fps_rff_kernel(const float* __restrict__ xyz,
                                                      float* __restrict__ out_xyz,
                                                      const float* __restrict__ feats,
                                                      const float* __restrict__ WfT,
                                                      unsigned short* __restrict__ RFFh) {
  __shared__ __align__(16) char smem[49152 + 256];
  if (blockIdx.x < 32)
    fps_body(smem, xyz, out_xyz, blockIdx.x);
  else
    rff_body(smem, feats, WfT, RFFh, blockIdx.x - 32);
}

// ---------------- ball query: one wave per (b,t,di,m), zero LDS -------------
__global__ __launch_bounds__(256) void ballq_kernel(const float* __restrict__ xyz,
                                                    const float* __restrict__ anchors,
                                                    int* __restrict__ idxbuf) {
  const float R2 = 0.04f;
  int w = threadIdx.x >> 6, lane = threadIdx.x & 63;
  int q = blockIdx.x * 4 + w;
  int m = q & (M - 1);
  int di = (q >> 10) % 3;
  int bt = q / (M * 3);
  int b = bt >> 3, t = bt & 7;
  int srct = t + di - 1;
  srct = srct < 0 ? 0 : (srct > 7 ? 7 : srct);
  const float* anc = anchors + ((size_t)(bt * M + m)) * 3;
  float ax = anc[0], ay = anc[1], az = anc[2];
  const float* pts = xyz + ((size_t)(b * T + srct)) * N * 3;
  int* outp = idxbuf + (size_t)q * KNN;
  int cnt = 0, first = 0;
  for (int c = 0; c < N / 64 && cnt < KNN; ++c) {
    int pi = c * 64 + lane;
    const float* pp = pts + (size_t)pi * 3;
    float dx = __fsub_rn(ax, pp[0]);
    float dy = __fsub_rn(ay, pp[1]);
    float dz = __fsub_rn(az, pp[2]);
    float d2 = __fadd_rn(__fadd_rn(__fmul_rn(dx, dx), __fmul_rn(dy, dy)), __fmul_rn(dz, dz));
    bool hit = d2 < R2;
    unsigned long long mask = __ballot(hit);
    if (cnt == 0 && mask) first = c * 64 + (int)__builtin_ctzll(mask);
    int prefix = (int)__popcll(mask & ((1ull << lane) - 1ull));
    int slot = cnt + prefix;
    if (hit && slot < KNN) outp[slot] = pi;
    cnt += (int)__popcll(mask);
  }
  int cntK = cnt < KNN ? cnt : KNN;
  int fill = (cnt == 0) ? 0 : first;
  if (lane < KNN && lane >= cntK) outp[lane] = fill;
}

// ---------------- fused gather(bf16) + packed dfeat + MFMA layer2 -----------
__global__ __launch_bounds__(256) void mlp_kernel(const float* __restrict__ xyz,
                                                  const unsigned short* __restrict__ RFFh,
                                                  const unsigned short* __restrict__ w1hi,
                                                  const float* __restrict__ WdP,
                                                  const float* __restrict__ anchors,
                                                  const int* __restrict__ idxbuf,
                                                  float* __restrict__ out_feats) {
  __shared__ unsigned short Ah[8192];
  __shared__ float wd_l[1024];
  __shared__ float fstage[4][128];
  int tid = threadIdx.x;
  {
    uint4* dh = (uint4*)Ah;
    const uint4* sh = (const uint4*)w1hi;
    for (int i = tid; i < 1024; i += 256) dh[i] = sh[i];
    wd_l[tid] = WdP[tid];
    wd_l[tid + 256] = WdP[tid + 256];
    wd_l[tid + 512] = WdP[tid + 512];
    wd_l[tid + 768] = WdP[tid + 768];
  }
  __syncthreads();
  int w = tid >> 6, lane = tid & 63;
  int nloc = lane & 15, grp = lane >> 4;
  // XCD-aware swizzle: 8192 blocks, 8 XCDs -> each XCD gets 1024 contiguous
  int bid = blockIdx.x;
  int swz = ((bid & 7) << 10) | (bid >> 3);
  int bt = swz >> 8;
  int m0 = (swz & 255) * 4;
  int m = m0 + w;
  int b = bt >> 3, t = bt & 7;
  int aoff = __builtin_amdgcn_readfirstlane(bt * M + m);
  float ax = anchors[(size_t)aoff * 3 + 0];
  float ay = anchors[(size_t)aoff * 3 + 1];
  float az = anchors[(size_t)aoff * 3 + 2];
  f32x4 acc[8];
#pragma unroll
  for (int mt = 0; mt < 8; ++mt) acc[mt] = (f32x4){0.f, 0.f, 0.f, 0.f};

  short8 pg0[2][2], pg1[2][2];  // [buf][kt] bf16 rff fragments
  float ppx[2][2], ppy[2][2], ppz[2][2];

#define MLOADP(BUF, DI)                                                        \
  {                                                                            \
    int srct = t + (DI)-1;                                                     \
    srct = srct < 0 ? 0 : (srct > 7 ? 7 : srct);                               \
    const unsigned short* rf = RFFh + ((size_t)(b * T + srct)) * N * 64;       \
    const float* pts = xyz + ((size_t)(b * T + srct)) * N * 3;                 \
    const int* ip = idxbuf + ((size_t)((bt * 3 + (DI)) * M + m)) * KNN;        \
    int n0 = ip[nloc], n1 = ip[16 + nloc];                                     \
    _Pragma("unroll") for (int kt = 0; kt < 2; ++kt) {                         \
      pg0[BUF][kt] = *(const short8*)(rf + (size_t)n0 * 64 + kt * 32 + grp * 8); \
      pg1[BUF][kt] = *(const short8*)(rf + (size_t)n1 * 64 + kt * 32 + grp * 8); \
    }                                                                          \
    ppx[BUF][0] = pts[n0 * 3 + 0];                                             \
    ppy[BUF][0] = pts[n0 * 3 + 1];                                             \
    ppz[BUF][0] = pts[n0 * 3 + 2];                                             \
    ppx[BUF][1] = pts[n1 * 3 + 0];                                             \
    ppy[BUF][1] = pts[n1 * 3 + 1];                                             \
    ppz[BUF][1] = pts[n1 * 3 + 2];                                             \
  }

#define MCOMPUTE(BUF, DI)                                                      \
  {                                                                            \
    int zro = 0;                                                               \
    asm volatile("" : "+v"(zro));                                              \
    const unsigned short* AhO = Ah + zro;                                      \
    const float* wdO = (const float*)wd_l + zro;                               \
    float tvv = (float)((DI)-1);                                               \
    f32x2 tv2 = (f32x2){tvv, tvv};                                             \
    f32x2 dx0 = (f32x2){ppx[BUF][0] - ax, ppx[BUF][0] - ax};                   \
    f32x2 dy0 = (f32x2){ppy[BUF][0] - ay, ppy[BUF][0] - ay};                   \
    f32x2 dz0 = (f32x2){ppz[BUF][0] - az, ppz[BUF][0] - az};                   \
    f32x2 dx1 = (f32x2){ppx[BUF][1] - ax, ppx[BUF][1] - ax};                   \
    f32x2 dy1 = (f32x2){ppy[BUF][1] - ay, ppy[BUF][1] - ay};                   \
    f32x2 dz1 = (f32x2){ppz[BUF][1] - az, ppz[BUF][1] - az};                   \
    f32x2 zz = (f32x2){0.f, 0.f};                                              \
    short8 Bh[2][2]; /* [kt][nt] */                                            \
    _Pragma("unroll") for (int kt = 0; kt < 2; ++kt) {                         \
      short8 bh0, bh1;                                                         \
      const unsigned* u0 = (const unsigned*)&pg0[BUF][kt];                     \
      const unsigned* u1 = (const unsigned*)&pg1[BUF][kt];                     \
      _Pragma("unroll") for (int p = 0; p < 4; ++p) {                          \
        const float* wp = wdO + ((kt * 8 + grp) * 4 + p) * 8;                  \
        f32x2 wc0 = *(const f32x2*)&wp[0];                                     \
        f32x2 wc1 = *(const f32x2*)&wp[2];                                     \
        f32x2 wc2 = *(const f32x2*)&wp[4];                                     \
        f32x2 wc3 = *(const f32x2*)&wp[6];                                     \
        f32x2 dd0 = wc0 * dx0 + wc1 * dy0 + wc2 * dz0 + wc3 * tv2;             \
        f32x2 dd1 = wc0 * dx1 + wc1 * dy1 + wc2 * dz1 + wc3 * tv2;             \
        dd0 = __builtin_elementwise_max(dd0, zz);                              \
        dd1 = __builtin_elementwise_max(dd1, zz);                              \
        unsigned a0u = u0[p], a1u = u1[p];                                     \
        f32x2 r0 = (f32x2){__uint_as_float(a0u << 16),                         \
                           __uint_as_float(a0u & 0xFFFF0000u)};                \
        f32x2 r1 = (f32x2){__uint_as_float(a1u << 16),                         \
                           __uint_as_float(a1u & 0xFFFF0000u)};                \
        f32x2 h0 = r0 + dd0, h1 = r1 + dd1;                                    \
        bh0[2 * p] = f2bf_rn(h0.x);                                            \
        bh0[2 * p + 1] = f2bf_rn(h0.y);                                        \
        bh1[2 * p] = f2bf_rn(h1.x);                                            \
        bh1[2 * p + 1] = f2bf_rn(h1.y);                                        \
      }                                                                        \
      Bh[kt][0] = bh0;                                                         \
      Bh[kt][1] = bh1;                                                         \
    }                                                                          \
    _Pragma("unroll") for (int hf = 0; hf < 2; ++hf) {                         \
      f32x4 c[4][2];                                                           \
      _Pragma("unroll") for (int mq = 0; mq < 4; ++mq) {                       \
        c[mq][0] = (f32x4){0.f, 0.f, 0.f, 0.f};                                \
        c[mq][1] = (f32x4){0.f, 0.f, 0.f, 0.f};                                \
      }                                                                        \
      _Pragma("unroll") for (int kt = 0; kt < 2; ++kt) {                       \
        _Pragma("unroll") for (int mq = 0; mq < 4; ++mq) {                     \
          int fo = ((kt * 8 + hf * 4 + mq) * 64 + lane) * 8;                   \
          short8 ahf = *(const short8*)&AhO[fo];                               \
          c[mq][0] =                                                           \
              __builtin_amdgcn_mfma_f32_16x16x32_bf16(ahf, Bh[kt][0], c[mq][0], 0, 0, 0); \
          c[mq][1] =                                                           \
              __builtin_amdgcn_mfma_f32_16x16x32_bf16(ahf, Bh[kt][1], c[mq][1], 0, 0, 0); \
        }                                                                      \
      }                                                                        \
      _Pragma("unroll") for (int mq = 0; mq < 4; ++mq)                         \
          _Pragma("unroll") for (int r = 0; r < 4; ++r) {                      \
        float o = fmaxf(c[mq][0][r], c[mq][1][r]);                             \
        o = fmaxf(o, dppf<0xB1>(o));                                           \
        o = fmaxf(o, dppf<0x4E>(o));                                           \
        o = fmaxf(o, dppf<0x141>(o));                                          \
        o = fmaxf(o, dppf<0x140>(o));                                          \
        acc[hf * 4 + mq][r] += fmaxf(o, 0.f);                                  \
      }                                                                        \
    }                                                                          \
  }

  MLOADP(0, 0)
  MLOADP(1, 1)
  MCOMPUTE(0, 0)
  MLOADP(0, 2)
  MCOMPUTE(1, 1)
  MCOMPUTE(0, 2)
#undef MLOADP
#undef MCOMPUTE

  if (nloc == 0) {
#pragma unroll
    for (int mt = 0; mt < 8; ++mt)
#pragma unroll
      for (int r = 0; r < 4; ++r)
        fstage[w][mt * 16 + grp * 4 + r] = acc[mt][r];
  }
  __syncthreads();
  if (tid < 128) {
    float4 v = make_float4(fstage[0][tid], fstage[1][tid], fstage[2][tid], fstage[3][tid]);
    *(float4*)&out_feats[((size_t)(bt * C1 + tid)) * M + m0] = v;
  }
}

extern "C" void kernel_launch(void* const* d_in, const int* in_sizes, int n_in,
                              void* d_out, int out_size, void* d_ws, size_t ws_size,
                              hipStream_t stream) {
  const float* xyzs = (const float*)d_in[0];
  const float* feats = (const float*)d_in[1];
  const float* Wd = (const float*)d_in[2];
  const float* Wf = (const float*)d_in[3];
  const float* W1 = (const float*)d_in[4];
  float* out_xyz = (float*)d_out;                            // (B,8,M,3)
  float* out_feats = (float*)d_out + (size_t)B * T * M * 3;  // (B,8,C1,M)
  char* ws = (char*)d_ws;
  unsigned short* RFFh = (unsigned short*)ws;                       // 16.78 MB
  int* idxbuf = (int*)(ws + (size_t)B * T * N * 64 * 2);            // 12.58 MB
  char* tail = ws + (size_t)B * T * N * 64 * 2 + (size_t)B * T * 3 * M * KNN * 4;
  float* WfT = (float*)tail;                                        // 16 KB
  unsigned short* w1hi = (unsigned short*)(tail + 16384);           // 16 KB
  float* WdP = (float*)(tail + 32768);                              // 4 KB
  prep_kernel<<<52, 256, 0, stream>>>(Wf, WfT, W1, w1hi, Wd, WdP);
  fps_rff_kernel<<<32 + 2048, 256, 0, stream>>>(xyzs, out_xyz, feats, WfT, RFFh);
  ballq_kernel<<<(B * T * 3 * M) / 4, 256, 0, stream>>>(xyzs, out_xyz, idxbuf);
  mlp_kernel<<<(B * T * M) / 4, 256, 0, stream>>>(xyzs, RFFh, w1hi, WdP, out_xyz,
                                                  idxbuf, out_feats);
}